// Round 18
// baseline (387.966 us; speedup 1.0000x reference)
//
#include <hip/hip_runtime.h>
#include <hip/hip_bf16.h>
#include <math.h>

#define Q_TOT 43200
#define H_ 120
#define W_ 360

typedef unsigned short ushort_t;
typedef float f32x4 __attribute__((ext_vector_type(4)));
typedef unsigned short u16x2 __attribute__((ext_vector_type(2)));
typedef unsigned short u16x4 __attribute__((ext_vector_type(4)));
typedef unsigned short u16x8 __attribute__((ext_vector_type(8)));
using short8 = __attribute__((ext_vector_type(8))) short;

static __device__ __forceinline__ float b2f(unsigned short u){
  return __uint_as_float(((unsigned)u) << 16);
}
static __device__ __forceinline__ unsigned short f2b(float f){
  unsigned u = __float_as_uint(f);
  unsigned r = (u + 0x7fffu + ((u >> 16) & 1u)) >> 16;  // RNE
  return (unsigned short)r;
}

#define SWZ(row, byte) ((byte) ^ (((row) & 7) << 4))

// ---------------- fp32 -> bf16 straight weight conversion ----------------
#define CVT_TOT 615072
__global__ __launch_bounds__(256) void cvt_kernel(
    const float* p0, const float* p1, const float* p2, const float* p3,
    const float* p4, const float* p5, const float* p6, const float* p7,
    const float* p8, const float* p9, const float* p10, const float* p11,
    const float* p12, const float* p13, const float* p14, const float* p15,
    const float* p16, const float* p17, const float* p18, const float* p19,
    ushort_t* __restrict__ dst){
  const float* ps[20] = {p0,p1,p2,p3,p4,p5,p6,p7,p8,p9,p10,p11,p12,p13,p14,p15,p16,p17,p18,p19};
  const int offs[20] = {0,65536,65664,90240,90432,102720,102816,151968,152352,201504,
                        201888,202272,202656,399264,400800,597408,597792,598176,598560,614944};
  int gid = blockIdx.x*256 + threadIdx.x;
  if (gid >= CVT_TOT) return;
  int s = 0;
  #pragma unroll
  for (int i=1;i<20;i++) s += (gid >= offs[i]) ? 1 : 0;
  dst[gid] = f2b(ps[s][gid - offs[s]]);
}

// ---- fp32 [L][K][N] -> bf16 [L][N][K]; last segment fuses off_w|aw_w into [96][128]
#define CVTT_TOT 528384
__global__ __launch_bounds__(256) void cvtT_kernel(
    const float* __restrict__ vw, const float* __restrict__ ow,
    const float* __restrict__ w1, const float* __restrict__ w2,
    const float* __restrict__ offw, const float* __restrict__ aww,
    ushort_t* __restrict__ dst){
  int gid = blockIdx.x*256 + threadIdx.x;
  if (gid >= CVTT_TOT) return;
  if (gid >= 491520){
    int e = gid - 491520;
    int l = e / 12288, rem = e - l*12288;
    int n = rem >> 7, k = rem & 127;
    float v = (n < 64) ? offw[((size_t)l*128 + k)*64 + n]
                       : aww [((size_t)l*128 + k)*32 + (n-64)];
    dst[gid] = f2b(v);
    return;
  }
  const float* s; int K, N, off;
  if (gid < 49152)      { s = vw; K = 128; N = 128; off = 0; }
  else if (gid < 98304) { s = ow; K = 128; N = 128; off = 49152; }
  else if (gid < 294912){ s = w1; K = 128; N = 512; off = 98304; }
  else                  { s = w2; K = 512; N = 128; off = 294912; }
  int e = gid - off;
  int per = K*N;
  int l = e / per, rem = e - l*per;
  int n = rem / K, k = rem - n*K;
  dst[gid] = f2b(s[(size_t)l*per + (size_t)k*N + n]);
}

// ---------------- separable pos tables: py[120][64] | px[360][64] ----------------
__global__ __launch_bounds__(256) void postab_kernel(float* __restrict__ tab){
  int gid = blockIdx.x*256 + threadIdx.x;
  if (gid >= 480*64) return;
  int row = gid >> 6, k = gid & 63;
  int m = k >> 1;
  float t = powf(10000.0f, (float)m * (1.0f/32.0f));
  float e;
  if (row < 120) e = (float)(row+1)   * (6.283185307179586f/((float)H_+1e-6f));
  else           e = (float)(row-119) * (6.283185307179586f/((float)W_+1e-6f));
  float p = e / t;
  tab[gid] = (k & 1) ? cosf(p) : sinf(p);
}

// -------- xT: x [512 c][Q] fp32 -> xbf [Q][512 c] bf16 (tiled via LDS) --------
__global__ __launch_bounds__(256) void xT_kernel(const float* __restrict__ x,
    ushort_t* __restrict__ xbf){
  __shared__ float t[32][65];
  const int tid = threadIdx.x;
  const int qt = blockIdx.x >> 4, ct = blockIdx.x & 15;
  const int q0 = qt * 64, c0 = ct * 32;
  {
    int row = tid >> 3, qoff = (tid & 7) * 8;
    const float* sp = x + (size_t)(c0 + row)*Q_TOT + q0 + qoff;
    f32x4 a = *(const f32x4*)sp;
    f32x4 b = *(const f32x4*)(sp + 4);
    #pragma unroll
    for (int j=0;j<4;j++){ t[row][qoff+j] = a[j]; t[row][qoff+4+j] = b[j]; }
  }
  __syncthreads();
  {
    int qrow = tid >> 2, cseg = (tid & 3) * 8;
    u16x8 pk;
    #pragma unroll
    for (int j=0;j<8;j++) pk[j] = f2b(t[cseg+j][qrow]);
    *(u16x8*)(xbf + (size_t)(q0 + qrow)*512 + c0 + cseg) = pk;
  }
}

// ----- merge v4 (ffn-style: 64-q, 8 waves, K=512 chunked dbuf) -> bf16 src -----
__global__ __launch_bounds__(512, 3) void merge_mfma(const ushort_t* __restrict__ xbf,
    const ushort_t* __restrict__ mw,   // [128 d][512 c] bf16
    const ushort_t* __restrict__ mb,
    ushort_t* __restrict__ srcbf){
  __shared__ ushort_t a_lds[2][64*128];   // 2 x 16KB, SWZ [64 q][128 c]
  const int tid = threadIdx.x;
  const int wave = tid >> 6, lane = tid & 63;
  const int lr = lane & 15, kg = lane >> 4;
  const int q0 = blockIdx.x * 64;
  const int drow = wave*16 + lr;          // this wave's d-rows
  #pragma unroll
  for (int i=0;i<2;i++){
    int idx = i*512 + tid;
    int row = idx >> 4, ch = idx & 15;
    u16x8 s = *(const u16x8*)(xbf + (size_t)(q0+row)*512 + ch*8);
    *(u16x8*)((char*)a_lds[0] + SWZ(row, row*256 + ch*16)) = s;
  }
  __syncthreads();
  f32x4 acc[4];
  #pragma unroll
  for (int qt=0; qt<4; qt++) acc[qt] = (f32x4){0.f,0.f,0.f,0.f};
  for (int ch = 0; ch < 4; ch++){
    u16x8 st[2];
    if (ch < 3){
      #pragma unroll
      for (int i=0;i<2;i++){
        int idx = i*512 + tid;
        int row = idx >> 4, cc = idx & 15;
        st[i] = *(const u16x8*)(xbf + (size_t)(q0+row)*512 + (ch+1)*128 + cc*8);
      }
    }
    short8 wf[4];
    #pragma unroll
    for (int ks=0; ks<4; ks++)
      wf[ks] = *(const short8*)(mw + (size_t)drow*512 + ch*128 + ks*32 + kg*8);
    const ushort_t* xb = a_lds[ch & 1];
    #pragma unroll
    for (int qt=0; qt<4; qt++){
      const int qrow = qt*16 + lr;
      short8 xf[4];
      #pragma unroll
      for (int ks=0; ks<4; ks++)
        xf[ks] = *(const short8*)((const char*)xb + SWZ(qrow, qrow*256 + (ks*32 + kg*8)*2));
      #pragma unroll
      for (int ks=0; ks<4; ks++)
        acc[qt] = __builtin_amdgcn_mfma_f32_16x16x32_bf16(xf[ks], wf[ks], acc[qt], 0, 0, 0);
    }
    if (ch < 3){
      ushort_t* xn = a_lds[(ch+1) & 1];
      #pragma unroll
      for (int i=0;i<2;i++){
        int idx = i*512 + tid;
        int row = idx >> 4, cc = idx & 15;
        *(u16x8*)((char*)xn + SWZ(row, row*256 + cc*16)) = st[i];
      }
      __syncthreads();
    }
  }
  float bb = b2f(mb[drow]);
  #pragma unroll
  for (int qt=0; qt<4; qt++){
    #pragma unroll
    for (int r=0; r<4; r++){
      int q = q0 + qt*16 + kg*4 + r;
      float vv = acc[qt][r] + bb;
      srcbf[(size_t)q*128 + drow] = f2b(vv > 0.f ? vv : 0.f);
    }
  }
}

// ------- fused qv (64-q tiles, bf16 src) — round-17 proven -------
__global__ __launch_bounds__(256, 3) void qv_mfma(const ushort_t* __restrict__ srcbf,
    const float* __restrict__ py, const float* __restrict__ px,
    const ushort_t* __restrict__ owt,  // [96 n][128 k] bf16
    const ushort_t* __restrict__ ob, const ushort_t* __restrict__ awb,
    const ushort_t* __restrict__ vwt,  // [128 n][128 k] bf16
    const ushort_t* __restrict__ vb,
    float* __restrict__ loc, float* __restrict__ awg,
    ushort_t* __restrict__ valbf){
  __shared__ ushort_t a_lds[64*128];
  __shared__ ushort_t qlds[64*128];
  const int tid = threadIdx.x;
  const int wave = tid >> 6, lane = tid & 63;
  const int lr = lane & 15, kg = lane >> 4;
  const int q0 = blockIdx.x * 64;
  #pragma unroll
  for (int i=0;i<4;i++){
    int idx = i*256 + tid;
    int row = idx >> 4, ch = idx & 15;
    int q = q0 + row, qy = q / W_, qx = q - qy*W_;
    u16x8 s = *(const u16x8*)(srcbf + (size_t)q*128 + ch*8);
    int c0 = ch*8;
    const float* tp = (c0 < 64) ? (py + qy*64 + c0) : (px + qx*64 + (c0-64));
    f32x4 t0 = *(const f32x4*)tp, t1 = *(const f32x4*)(tp+4);
    u16x8 pq;
    #pragma unroll
    for (int j=0;j<4;j++){
      pq[j]   = f2b(b2f(s[j])   + t0[j]);
      pq[4+j] = f2b(b2f(s[4+j]) + t1[j]);
    }
    int byte = row*256 + c0*2;
    *(u16x8*)((char*)a_lds + SWZ(row, byte)) = s;
    *(u16x8*)((char*)qlds + SWZ(row, byte)) = pq;
  }
  __syncthreads();
  const int qrow = wave*16 + lr;
  short8 xf[4], xq[4];
  #pragma unroll
  for (int ks=0; ks<4; ks++){
    xf[ks] = *(const short8*)((const char*)a_lds + SWZ(qrow, qrow*256 + (ks*32+kg*8)*2));
    xq[ks] = *(const short8*)((const char*)qlds + SWZ(qrow, qrow*256 + (ks*32+kg*8)*2));
  }
  f32x4 va[8];
  #pragma unroll
  for (int dt=0; dt<8; dt++) va[dt] = (f32x4){0.f,0.f,0.f,0.f};
  short8 yf[2][4];
  #pragma unroll
  for (int ks=0; ks<4; ks++)
    yf[0][ks] = *(const short8*)(vwt + (size_t)lr*128 + ks*32 + kg*8);
  #pragma unroll
  for (int dt=0; dt<8; dt++){
    if (dt < 7){
      const int nr = (dt+1)*16 + lr;
      #pragma unroll
      for (int ks=0; ks<4; ks++)
        yf[(dt+1)&1][ks] = *(const short8*)(vwt + (size_t)nr*128 + ks*32 + kg*8);
    }
    #pragma unroll
    for (int ks=0; ks<4; ks++)
      va[dt] = __builtin_amdgcn_mfma_f32_16x16x32_bf16(xf[ks], yf[dt&1][ks], va[dt], 0, 0, 0);
  }
  f32x4 qa[6];
  #pragma unroll
  for (int nt=0; nt<6; nt++) qa[nt] = (f32x4){0.f,0.f,0.f,0.f};
  short8 of[2][4];
  #pragma unroll
  for (int ks=0; ks<4; ks++)
    of[0][ks] = *(const short8*)(owt + (size_t)lr*128 + ks*32 + kg*8);
  #pragma unroll
  for (int nt=0; nt<6; nt++){
    if (nt < 5){
      const int nr = (nt+1)*16 + lr;
      #pragma unroll
      for (int ks=0; ks<4; ks++)
        of[(nt+1)&1][ks] = *(const short8*)(owt + (size_t)nr*128 + ks*32 + kg*8);
    }
    #pragma unroll
    for (int ks=0; ks<4; ks++)
      qa[nt] = __builtin_amdgcn_mfma_f32_16x16x32_bf16(xq[ks], of[nt&1][ks], qa[nt], 0, 0, 0);
  }
  #pragma unroll
  for (int dt=0; dt<8; dt++){
    float bb = b2f(vb[dt*16 + lr]);
    #pragma unroll
    for (int r=0; r<4; r++){
      int q = q0 + wave*16 + kg*4 + r;
      valbf[(size_t)q*128 + dt*16 + lr] = f2b(va[dt][r] + bb);
    }
  }
  #pragma unroll
  for (int r=0; r<4; r++){
    int q = q0 + wave*16 + kg*4 + r;
    int qy = q / W_, qx = q - qy*W_;
    float qxf = (float)qx, qyf = (float)qy;
    #pragma unroll
    for (int dt=0; dt<4; dt++){
      int n = dt*16 + lr;
      float v = qa[dt][r] + b2f(ob[n]);
      loc[(size_t)q*64 + n] = ((n & 1) ? qyf : qxf) + v;
    }
    #pragma unroll
    for (int d4=0; d4<2; d4++){
      int idx = d4*16 + lr;
      float v = qa[4+d4][r] + b2f(awb[idx]);
      float mx = fmaxf(v, __shfl_xor(v, 1, 64));
      mx = fmaxf(mx, __shfl_xor(mx, 2, 64));
      float e = expf(v - mx);
      float s = e + __shfl_xor(e, 1, 64);
      s = s + __shfl_xor(s, 2, 64);
      awg[(size_t)q*32 + idx] = e / s;
    }
  }
}

// ------- deformable bilinear sampling (8 q/block, 512 threads) -------
__global__ __launch_bounds__(512) void sample_kernel(const ushort_t* __restrict__ val,
    const float* __restrict__ loc, const float* __restrict__ awg,
    ushort_t* __restrict__ obf){
  __shared__ float sl[8][64];
  __shared__ float sa[8][32];
  const int tid = threadIdx.x;
  const int q0 = blockIdx.x * 8;
  sl[0][tid & 511] = loc[(size_t)q0*64 + tid];      // 512 floats
  if (tid < 256) sa[0][tid] = awg[(size_t)q0*32 + tid];
  __syncthreads();
  const int ql = tid >> 6, cp = (tid & 63) * 2;
  const int h = cp >> 4;
  float a0 = 0.f, a1 = 0.f;
  #pragma unroll
  for (int p=0;p<4;p++){
    float x = sl[ql][h*8 + p*2];
    float y = sl[ql][h*8 + p*2 + 1];
    float wgt = sa[ql][h*4 + p];
    float x0f = floorf(x), y0f = floorf(y);
    float wx = x - x0f, wy = y - y0f;
    int ix = (int)x0f, iy = (int)y0f;
    int x0c = min(max(ix, 0), W_-1),   x1c = min(max(ix+1, 0), W_-1);
    int y0c = min(max(iy, 0), H_-1),   y1c = min(max(iy+1, 0), H_-1);
    float vx0 = (ix   >= 0 && ix   < W_) ? 1.f : 0.f;
    float vx1 = (ix+1 >= 0 && ix+1 < W_) ? 1.f : 0.f;
    float vy0 = (iy   >= 0 && iy   < H_) ? 1.f : 0.f;
    float vy1 = (iy+1 >= 0 && iy+1 < H_) ? 1.f : 0.f;
    float w00 = (1.f-wx)*(1.f-wy)*vx0*vy0 * wgt;
    float w10 = wx*(1.f-wy)*vx1*vy0 * wgt;
    float w01 = (1.f-wx)*wy*vx0*vy1 * wgt;
    float w11 = wx*wy*vx1*vy1 * wgt;
    unsigned g00 = *(const unsigned*)(val + (size_t)(y0c*W_ + x0c)*128 + cp);
    unsigned g10 = *(const unsigned*)(val + (size_t)(y0c*W_ + x1c)*128 + cp);
    unsigned g01 = *(const unsigned*)(val + (size_t)(y1c*W_ + x0c)*128 + cp);
    unsigned g11 = *(const unsigned*)(val + (size_t)(y1c*W_ + x1c)*128 + cp);
    a0 += w00*b2f((ushort_t)g00) + w10*b2f((ushort_t)g10)
        + w01*b2f((ushort_t)g01) + w11*b2f((ushort_t)g11);
    a1 += w00*b2f((ushort_t)(g00>>16)) + w10*b2f((ushort_t)(g10>>16))
        + w01*b2f((ushort_t)(g01>>16)) + w11*b2f((ushort_t)(g11>>16));
  }
  unsigned pk = (unsigned)f2b(a0) | ((unsigned)f2b(a1) << 16);
  *(unsigned*)&obf[(size_t)(q0+ql)*128 + cp] = pk;
}

// ------- out-proj + residual + LN (64-q, bf16 I/O) — round-17 proven -------
__global__ __launch_bounds__(256, 3) void outln_mfma(const ushort_t* __restrict__ obf,
    const ushort_t* __restrict__ wt,
    const ushort_t* __restrict__ bias,
    const ushort_t* __restrict__ gs, const ushort_t* __restrict__ gb,
    ushort_t* srcbf){
  __shared__ ushort_t a_lds[64*128];
  const int tid = threadIdx.x;
  const int wave = tid >> 6, lane = tid & 63;
  const int lr = lane & 15, kg = lane >> 4;
  const int q0 = blockIdx.x * 64;
  #pragma unroll
  for (int i=0;i<4;i++){
    int idx = i*256 + tid;
    int row = idx >> 4, ch = idx & 15;
    u16x8 s = *(const u16x8*)(obf + (size_t)(q0+row)*128 + ch*8);
    *(u16x8*)((char*)a_lds + SWZ(row, row*256 + ch*16)) = s;
  }
  __syncthreads();
  const int qrow = wave*16 + lr;
  short8 xf[4];
  #pragma unroll
  for (int ks=0; ks<4; ks++)
    xf[ks] = *(const short8*)((const char*)a_lds + SWZ(qrow, qrow*256 + (ks*32+kg*8)*2));
  f32x4 acc[8];
  #pragma unroll
  for (int dt=0; dt<8; dt++) acc[dt] = (f32x4){0.f,0.f,0.f,0.f};
  short8 yf[2][4];
  #pragma unroll
  for (int ks=0; ks<4; ks++)
    yf[0][ks] = *(const short8*)(wt + (size_t)lr*128 + ks*32 + kg*8);
  #pragma unroll
  for (int dt=0; dt<8; dt++){
    if (dt < 7){
      const int nr = (dt+1)*16 + lr;
      #pragma unroll
      for (int ks=0; ks<4; ks++)
        yf[(dt+1)&1][ks] = *(const short8*)(wt + (size_t)nr*128 + ks*32 + kg*8);
    }
    #pragma unroll
    for (int ks=0; ks<4; ks++)
      acc[dt] = __builtin_amdgcn_mfma_f32_16x16x32_bf16(xf[ks], yf[dt&1][ks], acc[dt], 0, 0, 0);
  }
  float g4[8], be4[8], bi4[8];
  #pragma unroll
  for (int dt=0; dt<8; dt++){
    g4[dt] = b2f(gs[dt*16+lr]); be4[dt] = b2f(gb[dt*16+lr]); bi4[dt] = b2f(bias[dt*16+lr]);
  }
  #pragma unroll
  for (int r=0; r<4; r++){
    const int q = q0 + wave*16 + kg*4 + r;
    float vals[8];
    float s1 = 0.f, s2 = 0.f;
    #pragma unroll
    for (int dt=0; dt<8; dt++){
      float v = acc[dt][r] + bi4[dt] + b2f(srcbf[(size_t)q*128 + dt*16 + lr]);
      vals[dt] = v; s1 += v; s2 += v*v;
    }
    #pragma unroll
    for (int m=1; m<16; m<<=1){ s1 += __shfl_xor(s1, m, 64); s2 += __shfl_xor(s2, m, 64); }
    float mean = s1*(1.f/128.f);
    float var  = s2*(1.f/128.f) - mean*mean;
    float inv  = rsqrtf(var + 1e-5f);
    #pragma unroll
    for (int dt=0; dt<8; dt++)
      srcbf[(size_t)q*128 + dt*16 + lr] = f2b((vals[dt]-mean)*inv*g4[dt] + be4[dt]);
  }
}

// ------ fused FFN + residual + LN (64-q, 8 waves, bf16 I/O) — round-17 proven ---
__global__ __launch_bounds__(512, 4) void ffn_mfma(
    const ushort_t* __restrict__ w1t,  // [512 n][128 k] bf16
    const ushort_t* __restrict__ b1,
    const ushort_t* __restrict__ w2t,  // [128 n][512 k] bf16
    const ushort_t* __restrict__ b2,
    const ushort_t* __restrict__ gs, const ushort_t* __restrict__ gb,
    ushort_t* srcbf){
  __shared__ char smem[49152];
  ushort_t* a_lds = (ushort_t*)smem;            // 16KB [64][128] swizzled
  ushort_t* h_lds = (ushort_t*)(smem + 16384);  // 32KB [64][256] swizzled
  float* scr = (float*)smem;                    // [64][132] f32 overlay (epilogue)
  const int tid = threadIdx.x;
  const int wave = tid >> 6, lane = tid & 63;
  const int lr = lane & 15, kg = lane >> 4;
  const int q0 = blockIdx.x * 64;
  #pragma unroll
  for (int i=0;i<2;i++){
    int idx = i*512 + tid;
    int row = idx >> 4, ch = idx & 15;
    u16x8 s = *(const u16x8*)(srcbf + (size_t)(q0+row)*128 + ch*8);
    *(u16x8*)((char*)a_lds + SWZ(row, row*256 + ch*16)) = s;
  }
  const int drow = wave*16 + lr;
  f32x4 accd[4];
  #pragma unroll
  for (int qt=0; qt<4; qt++) accd[qt] = (f32x4){0.f,0.f,0.f,0.f};
  __syncthreads();
  for (int half=0; half<2; half++){
    short8 wf[2][4];
    #pragma unroll
    for (int nt=0; nt<2; nt++){
      const int nrow = (half*16 + wave*2 + nt)*16 + lr;
      #pragma unroll
      for (int ks=0; ks<4; ks++)
        wf[nt][ks] = *(const short8*)(w1t + (size_t)nrow*128 + ks*32 + kg*8);
    }
    short8 yg[8];
    #pragma unroll
    for (int ks=0; ks<8; ks++)
      yg[ks] = *(const short8*)(w2t + (size_t)drow*512 + half*256 + ks*32 + kg*8);
    #pragma unroll
    for (int nt=0; nt<2; nt++){
      const int ngt = half*16 + wave*2 + nt;
      u16x4 bb = *(const u16x4*)(b1 + ngt*16 + kg*4);
      float bf[4];
      #pragma unroll
      for (int j=0;j<4;j++) bf[j] = b2f(bb[j]);
      #pragma unroll
      for (int qt=0; qt<4; qt++){
        f32x4 acc = (f32x4){0.f,0.f,0.f,0.f};
        const int q = qt*16 + lr;
        #pragma unroll
        for (int ks=0; ks<4; ks++){
          short8 yf = *(const short8*)((const char*)a_lds + SWZ(q, q*256 + (ks*32 + kg*8)*2));
          acc = __builtin_amdgcn_mfma_f32_16x16x32_bf16(wf[nt][ks], yf, acc, 0, 0, 0);
        }
        const int nl = (ngt & 15)*16 + kg*4;
        u16x4 hp;
        #pragma unroll
        for (int r=0;r<4;r++){ float v = acc[r] + bf[r]; hp[r] = f2b(v > 0.f ? v : 0.f); }
        *(u16x4*)((char*)h_lds + SWZ(q, q*512 + nl*2)) = hp;
      }
    }
    __syncthreads();
    #pragma unroll
    for (int qt=0; qt<4; qt++){
      const int qrow = qt*16 + lr;
      short8 xh[8];
      #pragma unroll
      for (int ks=0; ks<8; ks++)
        xh[ks] = *(const short8*)((const char*)h_lds + SWZ(qrow, qrow*512 + (ks*32 + kg*8)*2));
      #pragma unroll
      for (int ks=0; ks<8; ks++)
        accd[qt] = __builtin_amdgcn_mfma_f32_16x16x32_bf16(xh[ks], yg[ks], accd[qt], 0, 0, 0);
    }
    __syncthreads();
  }
  #pragma unroll
  for (int qt=0; qt<4; qt++)
    #pragma unroll
    for (int r=0; r<4; r++)
      scr[(qt*16 + kg*4 + r)*132 + wave*16 + lr] = accd[qt][r];
  __syncthreads();
  {
    const int c = lane*2;
    float bi0 = b2f(b2[c]),  bi1 = b2f(b2[c+1]);
    float g0  = b2f(gs[c]),  g1  = b2f(gs[c+1]);
    float be0 = b2f(gb[c]),  be1 = b2f(gb[c+1]);
    #pragma unroll
    for (int i=0; i<8; i++){
      const int ql = wave*8 + i;
      unsigned rr = *(const unsigned*)(srcbf + (size_t)(q0+ql)*128 + c);
      float v0 = scr[ql*132 + c]     + bi0 + b2f((ushort_t)rr);
      float v1 = scr[ql*132 + c + 1] + bi1 + b2f((ushort_t)(rr >> 16));
      float s1 = v0 + v1, s2 = v0*v0 + v1*v1;
      #pragma unroll
      for (int m=1; m<64; m<<=1){ s1 += __shfl_xor(s1, m, 64); s2 += __shfl_xor(s2, m, 64); }
      float mean = s1*(1.f/128.f);
      float var  = s2*(1.f/128.f) - mean*mean;
      float inv  = rsqrtf(var + 1e-5f);
      float o0 = (v0-mean)*inv*g0 + be0;
      float o1 = (v1-mean)*inv*g1 + be1;
      unsigned pk = (unsigned)f2b(o0) | ((unsigned)f2b(o1) << 16);
      *(unsigned*)(srcbf + (size_t)(q0+ql)*128 + c) = pk;
    }
  }
}

// ---------------- outc (64-q, bf16 in) — round-17 proven ----------
__global__ __launch_bounds__(256, 3) void outc_mfma(const ushort_t* __restrict__ srcbf,
    const ushort_t* __restrict__ wt,
    const ushort_t* __restrict__ bias,
    float* __restrict__ outp){
  __shared__ ushort_t a_lds[64*128];
  const int tid = threadIdx.x;
  const int wave = tid >> 6, lane = tid & 63;
  const int lr = lane & 15, kg = lane >> 4;
  const int q0 = blockIdx.x * 64;
  #pragma unroll
  for (int i=0;i<4;i++){
    int idx = i*256 + tid;
    int row = idx >> 4, ch = idx & 15;
    u16x8 s = *(const u16x8*)(srcbf + (size_t)(q0+row)*128 + ch*8);
    *(u16x8*)((char*)a_lds + SWZ(row, row*256 + ch*16)) = s;
  }
  __syncthreads();
  const int qrow = wave*16 + lr;
  short8 xf[4];
  #pragma unroll
  for (int ks=0; ks<4; ks++)
    xf[ks] = *(const short8*)((const char*)a_lds + SWZ(qrow, qrow*256 + (ks*32+kg*8)*2));
  f32x4 acc[8];
  #pragma unroll
  for (int dt=0; dt<8; dt++) acc[dt] = (f32x4){0.f,0.f,0.f,0.f};
  short8 yf[2][4];
  #pragma unroll
  for (int ks=0; ks<4; ks++)
    yf[0][ks] = *(const short8*)(wt + (size_t)lr*128 + ks*32 + kg*8);
  #pragma unroll
  for (int dt=0; dt<8; dt++){
    if (dt < 7){
      const int nr = (dt+1)*16 + lr;
      #pragma unroll
      for (int ks=0; ks<4; ks++)
        yf[(dt+1)&1][ks] = *(const short8*)(wt + (size_t)nr*128 + ks*32 + kg*8);
    }
    #pragma unroll
    for (int ks=0; ks<4; ks++)
      acc[dt] = __builtin_amdgcn_mfma_f32_16x16x32_bf16(xf[ks], yf[dt&1][ks], acc[dt], 0, 0, 0);
  }
  #pragma unroll
  for (int dt=0; dt<8; dt++){
    float bb = b2f(bias[dt*16 + lr]);
    #pragma unroll
    for (int r=0; r<4; r++){
      int q = q0 + wave*16 + kg*4 + r;
      float v = acc[dt][r] + bb;
      v = v > 0.f ? v : 0.f;
      outp[(size_t)(dt*16 + lr)*Q_TOT + q] = v;
    }
  }
}

extern "C" void kernel_launch(void* const* d_in, const int* in_sizes, int n_in,
                              void* d_out, int out_size, void* d_ws, size_t ws_size,
                              hipStream_t stream){
  const float* x = (const float*)d_in[0];

  ushort_t* srcbf = (ushort_t*)d_ws;
  ushort_t* obf   = srcbf + (size_t)Q_TOT*128;
  ushort_t* valbf = obf   + (size_t)Q_TOT*128;
  float* loc = (float*)(valbf + (size_t)Q_TOT*128);
  float* aw  = loc + (size_t)Q_TOT*64;
  ushort_t* wbf   = (ushort_t*)(aw + (size_t)Q_TOT*32);
  ushort_t* tbase = wbf + 615072;
  float* postab = (float*)(tbase + 528384);
  float* pytab = postab;
  float* pxtab = postab + 120*64;
  ushort_t* xbf = (ushort_t*)(postab + 480*64);   // [Q][512] bf16 = 44.2 MB

  const ushort_t* mw     = wbf + 0;
  const ushort_t* mb     = wbf + 65536;
  const ushort_t* off_b  = wbf + 90240;
  const ushort_t* aw_b   = wbf + 102720;
  const ushort_t* val_b  = wbf + 151968;
  const ushort_t* out_b  = wbf + 201504;
  const ushort_t* n1_s   = wbf + 201888;
  const ushort_t* n1_b   = wbf + 202272;
  const ushort_t* l1_b   = wbf + 399264;
  const ushort_t* l2_b   = wbf + 597408;
  const ushort_t* n2_s   = wbf + 597792;
  const ushort_t* n2_b   = wbf + 598176;
  const ushort_t* outc_w = wbf + 598560;
  const ushort_t* outc_b = wbf + 614944;
  const ushort_t* val_wt = tbase + 0;
  const ushort_t* out_wt = tbase + 49152;
  const ushort_t* l1_wt  = tbase + 98304;
  const ushort_t* l2_wt  = tbase + 294912;
  const ushort_t* oaw_t  = tbase + 491520;

  cvt_kernel<<<(CVT_TOT+255)/256, 256, 0, stream>>>(
      (const float*)d_in[1],  (const float*)d_in[2],  (const float*)d_in[3],
      (const float*)d_in[4],  (const float*)d_in[5],  (const float*)d_in[6],
      (const float*)d_in[7],  (const float*)d_in[8],  (const float*)d_in[9],
      (const float*)d_in[10], (const float*)d_in[11], (const float*)d_in[12],
      (const float*)d_in[13], (const float*)d_in[14], (const float*)d_in[15],
      (const float*)d_in[16], (const float*)d_in[17], (const float*)d_in[18],
      (const float*)d_in[19], (const float*)d_in[20], wbf);
  cvtT_kernel<<<CVTT_TOT/256, 256, 0, stream>>>(
      (const float*)d_in[7], (const float*)d_in[9],
      (const float*)d_in[13], (const float*)d_in[15],
      (const float*)d_in[3], (const float*)d_in[5], tbase);
  postab_kernel<<<120, 256, 0, stream>>>(postab);

  xT_kernel<<<(Q_TOT/64)*16, 256, 0, stream>>>(x, xbf);
  merge_mfma<<<Q_TOT/64, 512, 0, stream>>>(xbf, mw, mb, srcbf);
  for (int l = 0; l < 3; l++){
    qv_mfma<<<Q_TOT/64, 256, 0, stream>>>(srcbf, pytab, pxtab,
        oaw_t + (size_t)l*96*128, off_b + (size_t)l*64, aw_b + (size_t)l*32,
        val_wt + (size_t)l*128*128, val_b + (size_t)l*128,
        loc, aw, valbf);
    sample_kernel<<<Q_TOT/8, 512, 0, stream>>>(valbf, loc, aw, obf);
    outln_mfma<<<Q_TOT/64, 256, 0, stream>>>(obf,
        out_wt + (size_t)l*128*128, out_b + (size_t)l*128,
        n1_s + (size_t)l*128, n1_b + (size_t)l*128, srcbf);
    ffn_mfma<<<Q_TOT/64, 512, 0, stream>>>(
        l1_wt + (size_t)l*512*128, l1_b + (size_t)l*512,
        l2_wt + (size_t)l*128*512, l2_b + (size_t)l*128,
        n2_s + (size_t)l*128, n2_b + (size_t)l*128, srcbf);
  }
  outc_mfma<<<Q_TOT/64, 256, 0, stream>>>(srcbf, outc_w, outc_b, (float*)d_out);
}

// Round 19
// 381.963 us; speedup vs baseline: 1.0157x; 1.0157x over previous
//
#include <hip/hip_runtime.h>
#include <hip/hip_bf16.h>
#include <math.h>

#define Q_TOT 43200
#define H_ 120
#define W_ 360

typedef unsigned short ushort_t;
typedef float f32x4 __attribute__((ext_vector_type(4)));
typedef unsigned short u16x2 __attribute__((ext_vector_type(2)));
typedef unsigned short u16x4 __attribute__((ext_vector_type(4)));
typedef unsigned short u16x8 __attribute__((ext_vector_type(8)));
using short8 = __attribute__((ext_vector_type(8))) short;

static __device__ __forceinline__ float b2f(unsigned short u){
  return __uint_as_float(((unsigned)u) << 16);
}
static __device__ __forceinline__ unsigned short f2b(float f){
  unsigned u = __float_as_uint(f);
  unsigned r = (u + 0x7fffu + ((u >> 16) & 1u)) >> 16;  // RNE
  return (unsigned short)r;
}

#define SWZ(row, byte) ((byte) ^ (((row) & 7) << 4))

// ---------------- fp32 -> bf16 straight weight conversion ----------------
#define CVT_TOT 615072
__global__ __launch_bounds__(256) void cvt_kernel(
    const float* p0, const float* p1, const float* p2, const float* p3,
    const float* p4, const float* p5, const float* p6, const float* p7,
    const float* p8, const float* p9, const float* p10, const float* p11,
    const float* p12, const float* p13, const float* p14, const float* p15,
    const float* p16, const float* p17, const float* p18, const float* p19,
    ushort_t* __restrict__ dst){
  const float* ps[20] = {p0,p1,p2,p3,p4,p5,p6,p7,p8,p9,p10,p11,p12,p13,p14,p15,p16,p17,p18,p19};
  const int offs[20] = {0,65536,65664,90240,90432,102720,102816,151968,152352,201504,
                        201888,202272,202656,399264,400800,597408,597792,598176,598560,614944};
  int gid = blockIdx.x*256 + threadIdx.x;
  if (gid >= CVT_TOT) return;
  int s = 0;
  #pragma unroll
  for (int i=1;i<20;i++) s += (gid >= offs[i]) ? 1 : 0;
  dst[gid] = f2b(ps[s][gid - offs[s]]);
}

// ---- fp32 [L][K][N] -> bf16 [L][N][K]; last segment fuses off_w|aw_w into [96][128]
#define CVTT_TOT 528384
__global__ __launch_bounds__(256) void cvtT_kernel(
    const float* __restrict__ vw, const float* __restrict__ ow,
    const float* __restrict__ w1, const float* __restrict__ w2,
    const float* __restrict__ offw, const float* __restrict__ aww,
    ushort_t* __restrict__ dst){
  int gid = blockIdx.x*256 + threadIdx.x;
  if (gid >= CVTT_TOT) return;
  if (gid >= 491520){
    int e = gid - 491520;
    int l = e / 12288, rem = e - l*12288;
    int n = rem >> 7, k = rem & 127;
    float v = (n < 64) ? offw[((size_t)l*128 + k)*64 + n]
                       : aww [((size_t)l*128 + k)*32 + (n-64)];
    dst[gid] = f2b(v);
    return;
  }
  const float* s; int K, N, off;
  if (gid < 49152)      { s = vw; K = 128; N = 128; off = 0; }
  else if (gid < 98304) { s = ow; K = 128; N = 128; off = 49152; }
  else if (gid < 294912){ s = w1; K = 128; N = 512; off = 98304; }
  else                  { s = w2; K = 512; N = 128; off = 294912; }
  int e = gid - off;
  int per = K*N;
  int l = e / per, rem = e - l*per;
  int n = rem / K, k = rem - n*K;
  dst[gid] = f2b(s[(size_t)l*per + (size_t)k*N + n]);
}

// ---------------- separable pos tables: py[120][64] | px[360][64] ----------------
__global__ __launch_bounds__(256) void postab_kernel(float* __restrict__ tab){
  int gid = blockIdx.x*256 + threadIdx.x;
  if (gid >= 480*64) return;
  int row = gid >> 6, k = gid & 63;
  int m = k >> 1;
  float t = powf(10000.0f, (float)m * (1.0f/32.0f));
  float e;
  if (row < 120) e = (float)(row+1)   * (6.283185307179586f/((float)H_+1e-6f));
  else           e = (float)(row-119) * (6.283185307179586f/((float)W_+1e-6f));
  float p = e / t;
  tab[gid] = (k & 1) ? cosf(p) : sinf(p);
}

// -------- xT: x [512 c][Q] fp32 -> xbf [Q][512 c] bf16 (tiled via LDS) --------
__global__ __launch_bounds__(256) void xT_kernel(const float* __restrict__ x,
    ushort_t* __restrict__ xbf){
  __shared__ float t[32][65];
  const int tid = threadIdx.x;
  const int qt = blockIdx.x >> 4, ct = blockIdx.x & 15;
  const int q0 = qt * 64, c0 = ct * 32;
  {
    int row = tid >> 3, qoff = (tid & 7) * 8;
    const float* sp = x + (size_t)(c0 + row)*Q_TOT + q0 + qoff;
    f32x4 a = *(const f32x4*)sp;
    f32x4 b = *(const f32x4*)(sp + 4);
    #pragma unroll
    for (int j=0;j<4;j++){ t[row][qoff+j] = a[j]; t[row][qoff+4+j] = b[j]; }
  }
  __syncthreads();
  {
    int qrow = tid >> 2, cseg = (tid & 3) * 8;
    u16x8 pk;
    #pragma unroll
    for (int j=0;j<8;j++) pk[j] = f2b(t[cseg+j][qrow]);
    *(u16x8*)(xbf + (size_t)(q0 + qrow)*512 + c0 + cseg) = pk;
  }
}

// ----- merge v4 (ffn-style: 64-q, 8 waves, K=512 chunked dbuf) -> bf16 src -----
__global__ __launch_bounds__(512, 3) void merge_mfma(const ushort_t* __restrict__ xbf,
    const ushort_t* __restrict__ mw,   // [128 d][512 c] bf16
    const ushort_t* __restrict__ mb,
    ushort_t* __restrict__ srcbf){
  __shared__ ushort_t a_lds[2][64*128];   // 2 x 16KB, SWZ [64 q][128 c]
  const int tid = threadIdx.x;
  const int wave = tid >> 6, lane = tid & 63;
  const int lr = lane & 15, kg = lane >> 4;
  const int q0 = blockIdx.x * 64;
  const int drow = wave*16 + lr;          // this wave's d-rows
  #pragma unroll
  for (int i=0;i<2;i++){
    int idx = i*512 + tid;
    int row = idx >> 4, ch = idx & 15;
    u16x8 s = *(const u16x8*)(xbf + (size_t)(q0+row)*512 + ch*8);
    *(u16x8*)((char*)a_lds[0] + SWZ(row, row*256 + ch*16)) = s;
  }
  __syncthreads();
  f32x4 acc[4];
  #pragma unroll
  for (int qt=0; qt<4; qt++) acc[qt] = (f32x4){0.f,0.f,0.f,0.f};
  for (int ch = 0; ch < 4; ch++){
    u16x8 st[2];
    if (ch < 3){
      #pragma unroll
      for (int i=0;i<2;i++){
        int idx = i*512 + tid;
        int row = idx >> 4, cc = idx & 15;
        st[i] = *(const u16x8*)(xbf + (size_t)(q0+row)*512 + (ch+1)*128 + cc*8);
      }
    }
    short8 wf[4];
    #pragma unroll
    for (int ks=0; ks<4; ks++)
      wf[ks] = *(const short8*)(mw + (size_t)drow*512 + ch*128 + ks*32 + kg*8);
    const ushort_t* xb = a_lds[ch & 1];
    #pragma unroll
    for (int qt=0; qt<4; qt++){
      const int qrow = qt*16 + lr;
      short8 xf[4];
      #pragma unroll
      for (int ks=0; ks<4; ks++)
        xf[ks] = *(const short8*)((const char*)xb + SWZ(qrow, qrow*256 + (ks*32 + kg*8)*2));
      #pragma unroll
      for (int ks=0; ks<4; ks++)
        acc[qt] = __builtin_amdgcn_mfma_f32_16x16x32_bf16(xf[ks], wf[ks], acc[qt], 0, 0, 0);
    }
    if (ch < 3){
      ushort_t* xn = a_lds[(ch+1) & 1];
      #pragma unroll
      for (int i=0;i<2;i++){
        int idx = i*512 + tid;
        int row = idx >> 4, cc = idx & 15;
        *(u16x8*)((char*)xn + SWZ(row, row*256 + cc*16)) = st[i];
      }
      __syncthreads();
    }
  }
  float bb = b2f(mb[drow]);
  #pragma unroll
  for (int qt=0; qt<4; qt++){
    #pragma unroll
    for (int r=0; r<4; r++){
      int q = q0 + qt*16 + kg*4 + r;
      float vv = acc[qt][r] + bb;
      srcbf[(size_t)q*128 + drow] = f2b(vv > 0.f ? vv : 0.f);
    }
  }
}

// ------- fused qv (64-q tiles, bf16 src) — round-17 proven -------
__global__ __launch_bounds__(256, 3) void qv_mfma(const ushort_t* __restrict__ srcbf,
    const float* __restrict__ py, const float* __restrict__ px,
    const ushort_t* __restrict__ owt,  // [96 n][128 k] bf16
    const ushort_t* __restrict__ ob, const ushort_t* __restrict__ awb,
    const ushort_t* __restrict__ vwt,  // [128 n][128 k] bf16
    const ushort_t* __restrict__ vb,
    float* __restrict__ loc, float* __restrict__ awg,
    ushort_t* __restrict__ valbf){
  __shared__ ushort_t a_lds[64*128];
  __shared__ ushort_t qlds[64*128];
  const int tid = threadIdx.x;
  const int wave = tid >> 6, lane = tid & 63;
  const int lr = lane & 15, kg = lane >> 4;
  const int q0 = blockIdx.x * 64;
  #pragma unroll
  for (int i=0;i<4;i++){
    int idx = i*256 + tid;
    int row = idx >> 4, ch = idx & 15;
    int q = q0 + row, qy = q / W_, qx = q - qy*W_;
    u16x8 s = *(const u16x8*)(srcbf + (size_t)q*128 + ch*8);
    int c0 = ch*8;
    const float* tp = (c0 < 64) ? (py + qy*64 + c0) : (px + qx*64 + (c0-64));
    f32x4 t0 = *(const f32x4*)tp, t1 = *(const f32x4*)(tp+4);
    u16x8 pq;
    #pragma unroll
    for (int j=0;j<4;j++){
      pq[j]   = f2b(b2f(s[j])   + t0[j]);
      pq[4+j] = f2b(b2f(s[4+j]) + t1[j]);
    }
    int byte = row*256 + c0*2;
    *(u16x8*)((char*)a_lds + SWZ(row, byte)) = s;
    *(u16x8*)((char*)qlds + SWZ(row, byte)) = pq;
  }
  __syncthreads();
  const int qrow = wave*16 + lr;
  short8 xf[4], xq[4];
  #pragma unroll
  for (int ks=0; ks<4; ks++){
    xf[ks] = *(const short8*)((const char*)a_lds + SWZ(qrow, qrow*256 + (ks*32+kg*8)*2));
    xq[ks] = *(const short8*)((const char*)qlds + SWZ(qrow, qrow*256 + (ks*32+kg*8)*2));
  }
  f32x4 va[8];
  #pragma unroll
  for (int dt=0; dt<8; dt++) va[dt] = (f32x4){0.f,0.f,0.f,0.f};
  short8 yf[2][4];
  #pragma unroll
  for (int ks=0; ks<4; ks++)
    yf[0][ks] = *(const short8*)(vwt + (size_t)lr*128 + ks*32 + kg*8);
  #pragma unroll
  for (int dt=0; dt<8; dt++){
    if (dt < 7){
      const int nr = (dt+1)*16 + lr;
      #pragma unroll
      for (int ks=0; ks<4; ks++)
        yf[(dt+1)&1][ks] = *(const short8*)(vwt + (size_t)nr*128 + ks*32 + kg*8);
    }
    #pragma unroll
    for (int ks=0; ks<4; ks++)
      va[dt] = __builtin_amdgcn_mfma_f32_16x16x32_bf16(xf[ks], yf[dt&1][ks], va[dt], 0, 0, 0);
  }
  f32x4 qa[6];
  #pragma unroll
  for (int nt=0; nt<6; nt++) qa[nt] = (f32x4){0.f,0.f,0.f,0.f};
  short8 of[2][4];
  #pragma unroll
  for (int ks=0; ks<4; ks++)
    of[0][ks] = *(const short8*)(owt + (size_t)lr*128 + ks*32 + kg*8);
  #pragma unroll
  for (int nt=0; nt<6; nt++){
    if (nt < 5){
      const int nr = (nt+1)*16 + lr;
      #pragma unroll
      for (int ks=0; ks<4; ks++)
        of[(nt+1)&1][ks] = *(const short8*)(owt + (size_t)nr*128 + ks*32 + kg*8);
    }
    #pragma unroll
    for (int ks=0; ks<4; ks++)
      qa[nt] = __builtin_amdgcn_mfma_f32_16x16x32_bf16(xq[ks], of[nt&1][ks], qa[nt], 0, 0, 0);
  }
  #pragma unroll
  for (int dt=0; dt<8; dt++){
    float bb = b2f(vb[dt*16 + lr]);
    #pragma unroll
    for (int r=0; r<4; r++){
      int q = q0 + wave*16 + kg*4 + r;
      valbf[(size_t)q*128 + dt*16 + lr] = f2b(va[dt][r] + bb);
    }
  }
  #pragma unroll
  for (int r=0; r<4; r++){
    int q = q0 + wave*16 + kg*4 + r;
    int qy = q / W_, qx = q - qy*W_;
    float qxf = (float)qx, qyf = (float)qy;
    #pragma unroll
    for (int dt=0; dt<4; dt++){
      int n = dt*16 + lr;
      float v = qa[dt][r] + b2f(ob[n]);
      loc[(size_t)q*64 + n] = ((n & 1) ? qyf : qxf) + v;
    }
    #pragma unroll
    for (int d4=0; d4<2; d4++){
      int idx = d4*16 + lr;
      float v = qa[4+d4][r] + b2f(awb[idx]);
      float mx = fmaxf(v, __shfl_xor(v, 1, 64));
      mx = fmaxf(mx, __shfl_xor(mx, 2, 64));
      float e = expf(v - mx);
      float s = e + __shfl_xor(e, 1, 64);
      s = s + __shfl_xor(s, 2, 64);
      awg[(size_t)q*32 + idx] = e / s;
    }
  }
}

// ---------------- deformable bilinear sampling (4 q/block) — round-17 proven ----
__global__ __launch_bounds__(256) void sample_kernel(const ushort_t* __restrict__ val,
    const float* __restrict__ loc, const float* __restrict__ awg,
    ushort_t* __restrict__ obf){
  __shared__ float sl[4][64];
  __shared__ float sa[4][32];
  const int tid = threadIdx.x;
  const int q0 = blockIdx.x * 4;
  sl[0][tid & 255] = loc[(size_t)q0*64 + tid];
  if (tid < 128) sa[0][tid] = awg[(size_t)q0*32 + tid];
  __syncthreads();
  const int ql = tid >> 6, cp = (tid & 63) * 2;
  const int h = cp >> 4;
  float a0 = 0.f, a1 = 0.f;
  #pragma unroll
  for (int p=0;p<4;p++){
    float x = sl[ql][h*8 + p*2];
    float y = sl[ql][h*8 + p*2 + 1];
    float wgt = sa[ql][h*4 + p];
    float x0f = floorf(x), y0f = floorf(y);
    float wx = x - x0f, wy = y - y0f;
    int ix = (int)x0f, iy = (int)y0f;
    int x0c = min(max(ix, 0), W_-1),   x1c = min(max(ix+1, 0), W_-1);
    int y0c = min(max(iy, 0), H_-1),   y1c = min(max(iy+1, 0), H_-1);
    float vx0 = (ix   >= 0 && ix   < W_) ? 1.f : 0.f;
    float vx1 = (ix+1 >= 0 && ix+1 < W_) ? 1.f : 0.f;
    float vy0 = (iy   >= 0 && iy   < H_) ? 1.f : 0.f;
    float vy1 = (iy+1 >= 0 && iy+1 < H_) ? 1.f : 0.f;
    float w00 = (1.f-wx)*(1.f-wy)*vx0*vy0 * wgt;
    float w10 = wx*(1.f-wy)*vx1*vy0 * wgt;
    float w01 = (1.f-wx)*wy*vx0*vy1 * wgt;
    float w11 = wx*wy*vx1*vy1 * wgt;
    unsigned g00 = *(const unsigned*)(val + (size_t)(y0c*W_ + x0c)*128 + cp);
    unsigned g10 = *(const unsigned*)(val + (size_t)(y0c*W_ + x1c)*128 + cp);
    unsigned g01 = *(const unsigned*)(val + (size_t)(y1c*W_ + x0c)*128 + cp);
    unsigned g11 = *(const unsigned*)(val + (size_t)(y1c*W_ + x1c)*128 + cp);
    a0 += w00*b2f((ushort_t)g00) + w10*b2f((ushort_t)g10)
        + w01*b2f((ushort_t)g01) + w11*b2f((ushort_t)g11);
    a1 += w00*b2f((ushort_t)(g00>>16)) + w10*b2f((ushort_t)(g10>>16))
        + w01*b2f((ushort_t)(g01>>16)) + w11*b2f((ushort_t)(g11>>16));
  }
  unsigned pk = (unsigned)f2b(a0) | ((unsigned)f2b(a1) << 16);
  *(unsigned*)&obf[(size_t)(q0+ql)*128 + cp] = pk;
}

// ------- out-proj + residual + LN (64-q, bf16 I/O) — round-17 proven -------
__global__ __launch_bounds__(256, 3) void outln_mfma(const ushort_t* __restrict__ obf,
    const ushort_t* __restrict__ wt,
    const ushort_t* __restrict__ bias,
    const ushort_t* __restrict__ gs, const ushort_t* __restrict__ gb,
    ushort_t* srcbf){
  __shared__ ushort_t a_lds[64*128];
  const int tid = threadIdx.x;
  const int wave = tid >> 6, lane = tid & 63;
  const int lr = lane & 15, kg = lane >> 4;
  const int q0 = blockIdx.x * 64;
  #pragma unroll
  for (int i=0;i<4;i++){
    int idx = i*256 + tid;
    int row = idx >> 4, ch = idx & 15;
    u16x8 s = *(const u16x8*)(obf + (size_t)(q0+row)*128 + ch*8);
    *(u16x8*)((char*)a_lds + SWZ(row, row*256 + ch*16)) = s;
  }
  __syncthreads();
  const int qrow = wave*16 + lr;
  short8 xf[4];
  #pragma unroll
  for (int ks=0; ks<4; ks++)
    xf[ks] = *(const short8*)((const char*)a_lds + SWZ(qrow, qrow*256 + (ks*32+kg*8)*2));
  f32x4 acc[8];
  #pragma unroll
  for (int dt=0; dt<8; dt++) acc[dt] = (f32x4){0.f,0.f,0.f,0.f};
  short8 yf[2][4];
  #pragma unroll
  for (int ks=0; ks<4; ks++)
    yf[0][ks] = *(const short8*)(wt + (size_t)lr*128 + ks*32 + kg*8);
  #pragma unroll
  for (int dt=0; dt<8; dt++){
    if (dt < 7){
      const int nr = (dt+1)*16 + lr;
      #pragma unroll
      for (int ks=0; ks<4; ks++)
        yf[(dt+1)&1][ks] = *(const short8*)(wt + (size_t)nr*128 + ks*32 + kg*8);
    }
    #pragma unroll
    for (int ks=0; ks<4; ks++)
      acc[dt] = __builtin_amdgcn_mfma_f32_16x16x32_bf16(xf[ks], yf[dt&1][ks], acc[dt], 0, 0, 0);
  }
  float g4[8], be4[8], bi4[8];
  #pragma unroll
  for (int dt=0; dt<8; dt++){
    g4[dt] = b2f(gs[dt*16+lr]); be4[dt] = b2f(gb[dt*16+lr]); bi4[dt] = b2f(bias[dt*16+lr]);
  }
  #pragma unroll
  for (int r=0; r<4; r++){
    const int q = q0 + wave*16 + kg*4 + r;
    float vals[8];
    float s1 = 0.f, s2 = 0.f;
    #pragma unroll
    for (int dt=0; dt<8; dt++){
      float v = acc[dt][r] + bi4[dt] + b2f(srcbf[(size_t)q*128 + dt*16 + lr]);
      vals[dt] = v; s1 += v; s2 += v*v;
    }
    #pragma unroll
    for (int m=1; m<16; m<<=1){ s1 += __shfl_xor(s1, m, 64); s2 += __shfl_xor(s2, m, 64); }
    float mean = s1*(1.f/128.f);
    float var  = s2*(1.f/128.f) - mean*mean;
    float inv  = rsqrtf(var + 1e-5f);
    #pragma unroll
    for (int dt=0; dt<8; dt++)
      srcbf[(size_t)q*128 + dt*16 + lr] = f2b((vals[dt]-mean)*inv*g4[dt] + be4[dt]);
  }
}

// ------ fused FFN + residual + LN (64-q, 8 waves, bf16 I/O) — round-17 proven ---
__global__ __launch_bounds__(512, 4) void ffn_mfma(
    const ushort_t* __restrict__ w1t,  // [512 n][128 k] bf16
    const ushort_t* __restrict__ b1,
    const ushort_t* __restrict__ w2t,  // [128 n][512 k] bf16
    const ushort_t* __restrict__ b2,
    const ushort_t* __restrict__ gs, const ushort_t* __restrict__ gb,
    ushort_t* srcbf){
  __shared__ char smem[49152];
  ushort_t* a_lds = (ushort_t*)smem;            // 16KB [64][128] swizzled
  ushort_t* h_lds = (ushort_t*)(smem + 16384);  // 32KB [64][256] swizzled
  float* scr = (float*)smem;                    // [64][132] f32 overlay (epilogue)
  const int tid = threadIdx.x;
  const int wave = tid >> 6, lane = tid & 63;
  const int lr = lane & 15, kg = lane >> 4;
  const int q0 = blockIdx.x * 64;
  #pragma unroll
  for (int i=0;i<2;i++){
    int idx = i*512 + tid;
    int row = idx >> 4, ch = idx & 15;
    u16x8 s = *(const u16x8*)(srcbf + (size_t)(q0+row)*128 + ch*8);
    *(u16x8*)((char*)a_lds + SWZ(row, row*256 + ch*16)) = s;
  }
  const int drow = wave*16 + lr;
  f32x4 accd[4];
  #pragma unroll
  for (int qt=0; qt<4; qt++) accd[qt] = (f32x4){0.f,0.f,0.f,0.f};
  __syncthreads();
  for (int half=0; half<2; half++){
    short8 wf[2][4];
    #pragma unroll
    for (int nt=0; nt<2; nt++){
      const int nrow = (half*16 + wave*2 + nt)*16 + lr;
      #pragma unroll
      for (int ks=0; ks<4; ks++)
        wf[nt][ks] = *(const short8*)(w1t + (size_t)nrow*128 + ks*32 + kg*8);
    }
    short8 yg[8];
    #pragma unroll
    for (int ks=0; ks<8; ks++)
      yg[ks] = *(const short8*)(w2t + (size_t)drow*512 + half*256 + ks*32 + kg*8);
    #pragma unroll
    for (int nt=0; nt<2; nt++){
      const int ngt = half*16 + wave*2 + nt;
      u16x4 bb = *(const u16x4*)(b1 + ngt*16 + kg*4);
      float bf[4];
      #pragma unroll
      for (int j=0;j<4;j++) bf[j] = b2f(bb[j]);
      #pragma unroll
      for (int qt=0; qt<4; qt++){
        f32x4 acc = (f32x4){0.f,0.f,0.f,0.f};
        const int q = qt*16 + lr;
        #pragma unroll
        for (int ks=0; ks<4; ks++){
          short8 yf = *(const short8*)((const char*)a_lds + SWZ(q, q*256 + (ks*32 + kg*8)*2));
          acc = __builtin_amdgcn_mfma_f32_16x16x32_bf16(wf[nt][ks], yf, acc, 0, 0, 0);
        }
        const int nl = (ngt & 15)*16 + kg*4;
        u16x4 hp;
        #pragma unroll
        for (int r=0;r<4;r++){ float v = acc[r] + bf[r]; hp[r] = f2b(v > 0.f ? v : 0.f); }
        *(u16x4*)((char*)h_lds + SWZ(q, q*512 + nl*2)) = hp;
      }
    }
    __syncthreads();
    #pragma unroll
    for (int qt=0; qt<4; qt++){
      const int qrow = qt*16 + lr;
      short8 xh[8];
      #pragma unroll
      for (int ks=0; ks<8; ks++)
        xh[ks] = *(const short8*)((const char*)h_lds + SWZ(qrow, qrow*512 + (ks*32 + kg*8)*2));
      #pragma unroll
      for (int ks=0; ks<8; ks++)
        accd[qt] = __builtin_amdgcn_mfma_f32_16x16x32_bf16(xh[ks], yg[ks], accd[qt], 0, 0, 0);
    }
    __syncthreads();
  }
  #pragma unroll
  for (int qt=0; qt<4; qt++)
    #pragma unroll
    for (int r=0; r<4; r++)
      scr[(qt*16 + kg*4 + r)*132 + wave*16 + lr] = accd[qt][r];
  __syncthreads();
  {
    const int c = lane*2;
    float bi0 = b2f(b2[c]),  bi1 = b2f(b2[c+1]);
    float g0  = b2f(gs[c]),  g1  = b2f(gs[c+1]);
    float be0 = b2f(gb[c]),  be1 = b2f(gb[c+1]);
    #pragma unroll
    for (int i=0; i<8; i++){
      const int ql = wave*8 + i;
      unsigned rr = *(const unsigned*)(srcbf + (size_t)(q0+ql)*128 + c);
      float v0 = scr[ql*132 + c]     + bi0 + b2f((ushort_t)rr);
      float v1 = scr[ql*132 + c + 1] + bi1 + b2f((ushort_t)(rr >> 16));
      float s1 = v0 + v1, s2 = v0*v0 + v1*v1;
      #pragma unroll
      for (int m=1; m<64; m<<=1){ s1 += __shfl_xor(s1, m, 64); s2 += __shfl_xor(s2, m, 64); }
      float mean = s1*(1.f/128.f);
      float var  = s2*(1.f/128.f) - mean*mean;
      float inv  = rsqrtf(var + 1e-5f);
      float o0 = (v0-mean)*inv*g0 + be0;
      float o1 = (v1-mean)*inv*g1 + be1;
      unsigned pk = (unsigned)f2b(o0) | ((unsigned)f2b(o1) << 16);
      *(unsigned*)(srcbf + (size_t)(q0+ql)*128 + c) = pk;
    }
  }
}

// ---------------- outc (64-q, bf16 in) — round-17 proven ----------
__global__ __launch_bounds__(256, 3) void outc_mfma(const ushort_t* __restrict__ srcbf,
    const ushort_t* __restrict__ wt,
    const ushort_t* __restrict__ bias,
    float* __restrict__ outp){
  __shared__ ushort_t a_lds[64*128];
  const int tid = threadIdx.x;
  const int wave = tid >> 6, lane = tid & 63;
  const int lr = lane & 15, kg = lane >> 4;
  const int q0 = blockIdx.x * 64;
  #pragma unroll
  for (int i=0;i<4;i++){
    int idx = i*256 + tid;
    int row = idx >> 4, ch = idx & 15;
    u16x8 s = *(const u16x8*)(srcbf + (size_t)(q0+row)*128 + ch*8);
    *(u16x8*)((char*)a_lds + SWZ(row, row*256 + ch*16)) = s;
  }
  __syncthreads();
  const int qrow = wave*16 + lr;
  short8 xf[4];
  #pragma unroll
  for (int ks=0; ks<4; ks++)
    xf[ks] = *(const short8*)((const char*)a_lds + SWZ(qrow, qrow*256 + (ks*32+kg*8)*2));
  f32x4 acc[8];
  #pragma unroll
  for (int dt=0; dt<8; dt++) acc[dt] = (f32x4){0.f,0.f,0.f,0.f};
  short8 yf[2][4];
  #pragma unroll
  for (int ks=0; ks<4; ks++)
    yf[0][ks] = *(const short8*)(wt + (size_t)lr*128 + ks*32 + kg*8);
  #pragma unroll
  for (int dt=0; dt<8; dt++){
    if (dt < 7){
      const int nr = (dt+1)*16 + lr;
      #pragma unroll
      for (int ks=0; ks<4; ks++)
        yf[(dt+1)&1][ks] = *(const short8*)(wt + (size_t)nr*128 + ks*32 + kg*8);
    }
    #pragma unroll
    for (int ks=0; ks<4; ks++)
      acc[dt] = __builtin_amdgcn_mfma_f32_16x16x32_bf16(xf[ks], yf[dt&1][ks], acc[dt], 0, 0, 0);
  }
  #pragma unroll
  for (int dt=0; dt<8; dt++){
    float bb = b2f(bias[dt*16 + lr]);
    #pragma unroll
    for (int r=0; r<4; r++){
      int q = q0 + wave*16 + kg*4 + r;
      float v = acc[dt][r] + bb;
      v = v > 0.f ? v : 0.f;
      outp[(size_t)(dt*16 + lr)*Q_TOT + q] = v;
    }
  }
}

extern "C" void kernel_launch(void* const* d_in, const int* in_sizes, int n_in,
                              void* d_out, int out_size, void* d_ws, size_t ws_size,
                              hipStream_t stream){
  const float* x = (const float*)d_in[0];

  ushort_t* srcbf = (ushort_t*)d_ws;
  ushort_t* obf   = srcbf + (size_t)Q_TOT*128;
  ushort_t* valbf = obf   + (size_t)Q_TOT*128;
  float* loc = (float*)(valbf + (size_t)Q_TOT*128);
  float* aw  = loc + (size_t)Q_TOT*64;
  ushort_t* wbf   = (ushort_t*)(aw + (size_t)Q_TOT*32);
  ushort_t* tbase = wbf + 615072;
  float* postab = (float*)(tbase + 528384);
  float* pytab = postab;
  float* pxtab = postab + 120*64;
  ushort_t* xbf = (ushort_t*)(postab + 480*64);   // [Q][512] bf16 = 44.2 MB

  const ushort_t* mw     = wbf + 0;
  const ushort_t* mb     = wbf + 65536;
  const ushort_t* off_b  = wbf + 90240;
  const ushort_t* aw_b   = wbf + 102720;
  const ushort_t* val_b  = wbf + 151968;
  const ushort_t* out_b  = wbf + 201504;
  const ushort_t* n1_s   = wbf + 201888;
  const ushort_t* n1_b   = wbf + 202272;
  const ushort_t* l1_b   = wbf + 399264;
  const ushort_t* l2_b   = wbf + 597408;
  const ushort_t* n2_s   = wbf + 597792;
  const ushort_t* n2_b   = wbf + 598176;
  const ushort_t* outc_w = wbf + 598560;
  const ushort_t* outc_b = wbf + 614944;
  const ushort_t* val_wt = tbase + 0;
  const ushort_t* out_wt = tbase + 49152;
  const ushort_t* l1_wt  = tbase + 98304;
  const ushort_t* l2_wt  = tbase + 294912;
  const ushort_t* oaw_t  = tbase + 491520;

  cvt_kernel<<<(CVT_TOT+255)/256, 256, 0, stream>>>(
      (const float*)d_in[1],  (const float*)d_in[2],  (const float*)d_in[3],
      (const float*)d_in[4],  (const float*)d_in[5],  (const float*)d_in[6],
      (const float*)d_in[7],  (const float*)d_in[8],  (const float*)d_in[9],
      (const float*)d_in[10], (const float*)d_in[11], (const float*)d_in[12],
      (const float*)d_in[13], (const float*)d_in[14], (const float*)d_in[15],
      (const float*)d_in[16], (const float*)d_in[17], (const float*)d_in[18],
      (const float*)d_in[19], (const float*)d_in[20], wbf);
  cvtT_kernel<<<CVTT_TOT/256, 256, 0, stream>>>(
      (const float*)d_in[7], (const float*)d_in[9],
      (const float*)d_in[13], (const float*)d_in[15],
      (const float*)d_in[3], (const float*)d_in[5], tbase);
  postab_kernel<<<120, 256, 0, stream>>>(postab);

  xT_kernel<<<(Q_TOT/64)*16, 256, 0, stream>>>(x, xbf);
  merge_mfma<<<Q_TOT/64, 512, 0, stream>>>(xbf, mw, mb, srcbf);
  for (int l = 0; l < 3; l++){
    qv_mfma<<<Q_TOT/64, 256, 0, stream>>>(srcbf, pytab, pxtab,
        oaw_t + (size_t)l*96*128, off_b + (size_t)l*64, aw_b + (size_t)l*32,
        val_wt + (size_t)l*128*128, val_b + (size_t)l*128,
        loc, aw, valbf);
    sample_kernel<<<Q_TOT/4, 256, 0, stream>>>(valbf, loc, aw, obf);
    outln_mfma<<<Q_TOT/64, 256, 0, stream>>>(obf,
        out_wt + (size_t)l*128*128, out_b + (size_t)l*128,
        n1_s + (size_t)l*128, n1_b + (size_t)l*128, srcbf);
    ffn_mfma<<<Q_TOT/64, 512, 0, stream>>>(
        l1_wt + (size_t)l*512*128, l1_b + (size_t)l*512,
        l2_wt + (size_t)l*128*512, l2_b + (size_t)l*128,
        n2_s + (size_t)l*128, n2_b + (size_t)l*128, srcbf);
  }
  outc_mfma<<<Q_TOT/64, 256, 0, stream>>>(srcbf, outc_w, outc_b, (float*)d_out);
}